// Round 1
// baseline (73.614 us; speedup 1.0000x reference)
//
#include <hip/hip_runtime.h>

#define HW   4096      // 64*64
#define NC   256
#define NTB  24        // 3 tensors * 8 batches
#define TOPK 2048      // max(1, int(0.5 * 4096))

// ---------------------------------------------------------------------------
// Pass A: imp[tb][hw] = (sum_{c=0..255, strictly sequential} |x[tb][c][hw]|) / 256
// Sequential single-accumulator per hw chain == numpy/XLA reduce order (bitwise).
// 2 chains per thread via float2 loads; unroll-8 batches independent loads.
// ---------------------------------------------------------------------------
__global__ __launch_bounds__(256) void k_imp(const float* __restrict__ i0,
                                             const float* __restrict__ i1,
                                             const float* __restrict__ i2,
                                             float* __restrict__ imp) {
  int tid = blockIdx.x * 256 + threadIdx.x;   // 0 .. 49151
  int hw2 = tid & (HW / 2 - 1);               // float2 index within row
  int tb  = tid >> 11;                        // 0 .. 23
  int t   = tb >> 3;
  const float* base = (t == 0 ? i0 : (t == 1 ? i1 : i2));
  const float2* p = reinterpret_cast<const float2*>(base + (size_t)(tb & 7) * NC * HW) + hw2;
  float s0 = 0.f, s1 = 0.f;
#pragma unroll 8
  for (int c = 0; c < NC; ++c) {
    float2 v = p[c * (HW / 2)];
    s0 += fabsf(v.x);                         // program order preserved per chain
    s1 += fabsf(v.y);
  }
  float2 m;
  m.x = s0 * (1.0f / 256.0f);                 // exact pow2 scale == /256.0
  m.y = s1 * (1.0f / 256.0f);
  reinterpret_cast<float2*>(imp)[tid] = m;
}

// ---------------------------------------------------------------------------
// Pass B: one block per (tensor,batch). Binary-search k-th largest on uint bits
// (all imp >= 0 so uint compare == float compare). Stable-top_k tie handling:
// among values == threshold, the lowest spatial indices are selected.
// Mask (0/1 floats) overwrites imp in place.
// ---------------------------------------------------------------------------
__global__ __launch_bounds__(1024) void k_select(float* __restrict__ impmask) {
  const int tb   = blockIdx.x;
  float* base    = impmask + (size_t)tb * HW;
  const int tid  = threadIdx.x;
  const int lane = tid & 63;
  const int wave = tid >> 6;

  float4 v = reinterpret_cast<const float4*>(base)[tid];
  unsigned u0 = __float_as_uint(v.x);
  unsigned u1 = __float_as_uint(v.y);
  unsigned u2 = __float_as_uint(v.z);
  unsigned u3 = __float_as_uint(v.w);

  __shared__ int s_red[16];
  __shared__ int s_b;
  __shared__ int s_eq[16];
  __shared__ int s_eqpre[16];
  __shared__ int s_gt_tot;

  // invariant: cnt_ge(lo) >= K  (all values >= 0), cnt_ge(hi) < K (no infs)
  unsigned lo = 0u, hi = 0x7F800000u;
  while (hi - lo > 1u) {
    unsigned mid = lo + ((hi - lo) >> 1);
    int c = (u0 >= mid) + (u1 >= mid) + (u2 >= mid) + (u3 >= mid);
#pragma unroll
    for (int off = 32; off > 0; off >>= 1) c += __shfl_xor(c, off, 64);
    if (lane == 0) s_red[wave] = c;
    __syncthreads();
    if (tid == 0) {
      int tot = 0;
#pragma unroll
      for (int w = 0; w < 16; ++w) tot += s_red[w];
      s_b = tot;
    }
    __syncthreads();
    int cnt = s_b;                 // uniform -> loop trip count uniform
    if (cnt >= TOPK) lo = mid; else hi = mid;
  }
  const unsigned thr = lo;         // bits of the k-th largest value

  int e0 = (u0 == thr), e1 = (u1 == thr), e2 = (u2 == thr), e3 = (u3 == thr);
  int g0 = (u0 > thr),  g1 = (u1 > thr),  g2 = (u2 > thr),  g3 = (u3 > thr);
  int eq = e0 + e1 + e2 + e3;
  int gt = g0 + g1 + g2 + g3;

  // block total of gt
#pragma unroll
  for (int off = 32; off > 0; off >>= 1) gt += __shfl_xor(gt, off, 64);
  __syncthreads();
  if (lane == 0) s_red[wave] = gt;

  // wave-inclusive scan of per-thread eq counts (thread order == index order)
  int incl = eq;
#pragma unroll
  for (int off = 1; off < 64; off <<= 1) {
    int n = __shfl_up(incl, off, 64);
    if (lane >= off) incl += n;
  }
  int wave_eq_tot = __shfl(incl, 63, 64);
  if (lane == 0) s_eq[wave] = wave_eq_tot;
  __syncthreads();
  if (tid == 0) {
    int tot = 0;
#pragma unroll
    for (int w = 0; w < 16; ++w) tot += s_red[w];
    s_gt_tot = tot;
    int run = 0;
#pragma unroll
    for (int w = 0; w < 16; ++w) { s_eqpre[w] = run; run += s_eq[w]; }
  }
  __syncthreads();

  const int needed  = TOPK - s_gt_tot;          // how many tied values to keep
  const int base_eq = s_eqpre[wave] + (incl - eq);  // exclusive prefix, this thread

  int r0 = base_eq;
  int r1 = base_eq + e0;
  int r2 = base_eq + e0 + e1;
  int r3 = base_eq + e0 + e1 + e2;

  float4 m;
  m.x = (g0 || (e0 && r0 < needed)) ? 1.f : 0.f;
  m.y = (g1 || (e1 && r1 < needed)) ? 1.f : 0.f;
  m.z = (g2 || (e2 && r2 < needed)) ? 1.f : 0.f;
  m.w = (g3 || (e3 && r3 < needed)) ? 1.f : 0.f;
  reinterpret_cast<float4*>(base)[tid] = m;
}

// ---------------------------------------------------------------------------
// Pass C: out = in * mask (float4 per thread). Mask tile is 16 KB/(t,b) -> cached.
// ---------------------------------------------------------------------------
__global__ __launch_bounds__(256) void k_apply(const float4* __restrict__ i0,
                                               const float4* __restrict__ i1,
                                               const float4* __restrict__ i2,
                                               const float4* __restrict__ mask,
                                               float4* __restrict__ out) {
  int i = blockIdx.x * 256 + threadIdx.x;   // 0 .. 6291455 (float4 units)
  int hw4 = i & 1023;                        // float4 col within row
  int tb  = i >> 18;                         // (t*8 + b); 2^18 float4 per (t,b)
  int t   = tb >> 3;
  const float4* src = (t == 0 ? i0 : (t == 1 ? i1 : i2));
  float4 a = src[i - (t << 21)];             // 2^21 float4 per tensor
  float4 m = mask[(tb << 10) | hw4];
  float4 r;
  r.x = a.x * m.x;
  r.y = a.y * m.y;
  r.z = a.z * m.z;
  r.w = a.w * m.w;
  out[i] = r;
}

extern "C" void kernel_launch(void* const* d_in, const int* in_sizes, int n_in,
                              void* d_out, int out_size, void* d_ws, size_t ws_size,
                              hipStream_t stream) {
  const float* i0 = (const float*)d_in[0];
  const float* i1 = (const float*)d_in[1];
  const float* i2 = (const float*)d_in[2];
  float* imp = (float*)d_ws;   // 3*8*4096 floats = 384 KB of scratch

  k_imp<<<192, 256, 0, stream>>>(i0, i1, i2, imp);
  k_select<<<NTB, 1024, 0, stream>>>(imp);
  k_apply<<<24576, 256, 0, stream>>>((const float4*)i0, (const float4*)i1,
                                     (const float4*)i2, (const float4*)imp,
                                     (float4*)d_out);
}

// Round 3
// 71.110 us; speedup vs baseline: 1.0352x; 1.0352x over previous
//
#include <hip/hip_runtime.h>

#define HW   4096      // 64*64
#define NC   256
#define NTB  24        // 3 tensors * 8 batches
#define TOPK 2048      // max(1, int(0.5 * 4096))

typedef float  vf4 __attribute__((ext_vector_type(4)));   // native vec: ok for nontemporal builtins
typedef float  vf2 __attribute__((ext_vector_type(2)));

// ---------------------------------------------------------------------------
// Pass A: imp[tb][hw] = (sum_{c=0..255, strictly sequential} |x[tb][c][hw]|) / 256
// Sequential single-accumulator per hw chain == numpy reduce order (bitwise).
// 2 chains per thread via float2 loads; unroll-16 keeps 128 B/lane in flight.
// ---------------------------------------------------------------------------
__global__ __launch_bounds__(256) void k_imp(const float* __restrict__ i0,
                                             const float* __restrict__ i1,
                                             const float* __restrict__ i2,
                                             float* __restrict__ imp) {
  int tid = blockIdx.x * 256 + threadIdx.x;   // 0 .. 49151
  int hw2 = tid & (HW / 2 - 1);               // float2 index within row
  int tb  = tid >> 11;                        // 0 .. 23
  int t   = tb >> 3;
  const float* base = (t == 0 ? i0 : (t == 1 ? i1 : i2));
  const vf2* p = reinterpret_cast<const vf2*>(base + (size_t)(tb & 7) * NC * HW) + hw2;
  float s0 = 0.f, s1 = 0.f;
#pragma unroll 16
  for (int c = 0; c < NC; ++c) {
    vf2 v = p[c * (HW / 2)];
    s0 += fabsf(v.x);                         // program order preserved per chain
    s1 += fabsf(v.y);
  }
  vf2 m;
  m.x = s0 * (1.0f / 256.0f);                 // exact pow2 scale == /256.0
  m.y = s1 * (1.0f / 256.0f);
  reinterpret_cast<vf2*>(imp)[tid] = m;
}

// ---------------------------------------------------------------------------
// Pass B: ONE WAVE per (tensor,batch) row. All 4096 values live in registers
// (64 per lane, lane l holds hw [l*64, l*64+64) -> lane-chunk order == index
// order). Binary search k-th largest on uint bits (all imp >= 0 so uint
// compare == float compare); min/max prescan narrows the range to ~20 iters.
// No __syncthreads anywhere. Stable-top_k ties: lowest indices win.
// Mask (0/1 floats) overwrites imp in place.
// ---------------------------------------------------------------------------
__global__ __launch_bounds__(64) void k_select(float* __restrict__ impmask) {
  const int tb   = blockIdx.x;
  float* base    = impmask + (size_t)tb * HW;
  const int lane = threadIdx.x;

  unsigned u[64];
  const vf4* p = reinterpret_cast<const vf4*>(base + lane * 64);
#pragma unroll
  for (int j = 0; j < 16; ++j) {
    vf4 v = p[j];
    u[4 * j + 0] = __float_as_uint(v.x);
    u[4 * j + 1] = __float_as_uint(v.y);
    u[4 * j + 2] = __float_as_uint(v.z);
    u[4 * j + 3] = __float_as_uint(v.w);
  }

  // prescan: tight initial [lo, hi) from actual min/max
  unsigned mx = 0u, mn = 0xFFFFFFFFu;
#pragma unroll
  for (int j = 0; j < 64; ++j) {
    mx = (u[j] > mx) ? u[j] : mx;
    mn = (u[j] < mn) ? u[j] : mn;
  }
#pragma unroll
  for (int off = 32; off > 0; off >>= 1) {
    unsigned ox = (unsigned)__shfl_xor((int)mx, off, 64);
    unsigned on = (unsigned)__shfl_xor((int)mn, off, 64);
    mx = (ox > mx) ? ox : mx;
    mn = (on < mn) ? on : mn;
  }

  // invariant: cnt_ge(lo) >= K  (lo=min -> 4096), cnt_ge(hi) < K (hi=max+1 -> 0)
  unsigned lo = mn, hi = mx + 1u;
  while (hi - lo > 1u) {
    unsigned mid = lo + ((hi - lo) >> 1);
    int c = 0;
#pragma unroll
    for (int j = 0; j < 64; ++j) c += (u[j] >= mid);
#pragma unroll
    for (int off = 32; off > 0; off >>= 1) c += __shfl_xor(c, off, 64);
    if (c >= TOPK) lo = mid; else hi = mid;   // c uniform across lanes
  }
  const unsigned thr = lo;                    // bits of the k-th largest value

  int eq = 0, gt = 0;
#pragma unroll
  for (int j = 0; j < 64; ++j) {
    eq += (u[j] == thr);
    gt += (u[j] > thr);
  }
  int g_tot = gt;
#pragma unroll
  for (int off = 32; off > 0; off >>= 1) g_tot += __shfl_xor(g_tot, off, 64);

  // exclusive prefix of eq-counts across lanes (lane order == index order)
  int incl = eq;
#pragma unroll
  for (int off = 1; off < 64; off <<= 1) {
    int n = __shfl_up(incl, off, 64);
    if (lane >= off) incl += n;
  }
  int r = incl - eq;                          // this lane's starting tie-rank
  const int needed = TOPK - g_tot;            // how many tied values to keep

  vf4* q = reinterpret_cast<vf4*>(base + lane * 64);
#pragma unroll
  for (int j = 0; j < 16; ++j) {
    float mv[4];
#pragma unroll
    for (int s = 0; s < 4; ++s) {
      unsigned x = u[4 * j + s];
      int e = (x == thr);
      mv[s] = (x > thr || (e && r < needed)) ? 1.f : 0.f;
      r += e;
    }
    vf4 m;
    m.x = mv[0]; m.y = mv[1]; m.z = mv[2]; m.w = mv[3];
    q[j] = m;
  }
}

// ---------------------------------------------------------------------------
// Pass C: out = in * mask (vf4 per thread). Mask tile is 16 KB/(t,b) ->
// cached. Nontemporal output stores: don't let the 96 MB write-allocate evict
// the input from L3 before we've re-read it.
// ---------------------------------------------------------------------------
__global__ __launch_bounds__(256) void k_apply(const vf4* __restrict__ i0,
                                               const vf4* __restrict__ i1,
                                               const vf4* __restrict__ i2,
                                               const vf4* __restrict__ mask,
                                               vf4* __restrict__ out) {
  int i = blockIdx.x * 256 + threadIdx.x;   // 0 .. 6291455 (vf4 units)
  int hw4 = i & 1023;                        // vf4 col within row
  int tb  = i >> 18;                         // (t*8 + b); 2^18 vf4 per (t,b)
  int t   = tb >> 3;
  const vf4* src = (t == 0 ? i0 : (t == 1 ? i1 : i2));
  vf4 a = src[i - (t << 21)];                // 2^21 vf4 per tensor
  vf4 m = mask[(tb << 10) | hw4];
  vf4 r = a * m;
  __builtin_nontemporal_store(r, &out[i]);
}

extern "C" void kernel_launch(void* const* d_in, const int* in_sizes, int n_in,
                              void* d_out, int out_size, void* d_ws, size_t ws_size,
                              hipStream_t stream) {
  const float* i0 = (const float*)d_in[0];
  const float* i1 = (const float*)d_in[1];
  const float* i2 = (const float*)d_in[2];
  float* imp = (float*)d_ws;   // 3*8*4096 floats = 384 KB of scratch

  k_imp<<<192, 256, 0, stream>>>(i0, i1, i2, imp);
  k_select<<<NTB, 64, 0, stream>>>(imp);
  k_apply<<<24576, 256, 0, stream>>>((const vf4*)i0, (const vf4*)i1,
                                     (const vf4*)i2, (const vf4*)imp,
                                     (vf4*)d_out);
}